// Round 8
// baseline (274.508 us; speedup 1.0000x reference)
//
#include <hip/hip_runtime.h>

namespace {

constexpr int B = 2, L = 4096, D = 512, H = 8, FF = 2048;
constexpr int M = B * L; // 8192
constexpr float LN_EPS = 1e-5f;

typedef __attribute__((ext_vector_type(8))) short short8;
typedef __attribute__((ext_vector_type(4))) float floatx4;

typedef __attribute__((address_space(3))) unsigned int lds_uint;
typedef const __attribute__((address_space(1))) unsigned int glob_uint;

__device__ __forceinline__ void gl_lds16(const unsigned short* g, unsigned short* l) {
  // async global->LDS, 16B/lane; LDS dest = wave-uniform base + lane*16 (m104)
  __builtin_amdgcn_global_load_lds((glob_uint*)g, (lds_uint*)l, 16, 0, 0);
}

__device__ __forceinline__ unsigned short f2bf(float f) {
  union { float f; unsigned u; } v; v.f = f;
  unsigned r = v.u + 0x7FFFu + ((v.u >> 16) & 1u);
  return (unsigned short)(r >> 16);
}

// ---------------- fused prep: x->bf16 + bias concat + weight transposes ------
// blocks [0,4102): x cast + bqkv. blocks [4102, 4870): 64x64 transpose tiles.
__global__ __launch_bounds__(256)
void k_prep(const float* __restrict__ x,
            const float* __restrict__ Wq, const float* __restrict__ Wk,
            const float* __restrict__ Wv, const float* __restrict__ Wo,
            const float* __restrict__ W1, const float* __restrict__ W2,
            const float* __restrict__ bq, const float* __restrict__ bk,
            const float* __restrict__ bv,
            unsigned short* __restrict__ Xb,
            unsigned short* __restrict__ WqkvT, unsigned short* __restrict__ WoT,
            unsigned short* __restrict__ W1T, unsigned short* __restrict__ W2T,
            float* __restrict__ bqkv) {
  __shared__ unsigned short tile[64 * 72];
  if (blockIdx.x < 4102) {
    int tid = blockIdx.x * blockDim.x + threadIdx.x;
    if (tid < 1048576) {  // x: 4 elems per thread (M*D = 4194304)
      float4 v = ((const float4*)x)[tid];
      ((ushort4*)Xb)[tid] = make_ushort4(f2bf(v.x), f2bf(v.y), f2bf(v.z), f2bf(v.w));
      return;
    }
    int u = tid - 1048576;
    if (u < 1536) bqkv[u] = (u < 512) ? bq[u] : (u < 1024 ? bk[u - 512] : bv[u - 1024]);
    return;
  }
  const int t = blockIdx.x - 4102;
  const float* src; unsigned short* dst; int Ns, Kd, n0, k0, nsrc0;
  if (t < 192) {        // WqkvT [1536][512] from Wq/Wk/Wv [512][512]
    int nt = t % 24, kt = t / 24; int ng = nt * 64;
    src = ng < 512 ? Wq : (ng < 1024 ? Wk : Wv);
    Ns = 512; Kd = 512; n0 = ng; nsrc0 = ng & 511; k0 = kt * 64; dst = WqkvT;
  } else if (t < 256) { // WoT [512][512] from Wo [512][512]
    int u = t - 192; int nt = u % 8, kt = u / 8;
    src = Wo; Ns = 512; Kd = 512; n0 = nt * 64; nsrc0 = n0; k0 = kt * 64; dst = WoT;
  } else if (t < 512) { // W1T [2048][512] from W1 [512][2048]
    int u = t - 256; int nt = u % 32, kt = u / 32;
    src = W1; Ns = 2048; Kd = 512; n0 = nt * 64; nsrc0 = n0; k0 = kt * 64; dst = W1T;
  } else {              // W2T [512][2048] from W2 [2048][512]
    int u = t - 512; int nt = u % 8, kt = u / 8;
    src = W2; Ns = 512; Kd = 2048; n0 = nt * 64; nsrc0 = n0; k0 = kt * 64; dst = W2T;
  }
  const int tid = threadIdx.x;
  {
    int r = tid >> 2, cs = (tid & 3) * 16;  // src row k0+r, 16 cols
    const float4* sp = (const float4*)(src + (size_t)(k0 + r) * Ns + nsrc0 + cs);
    unsigned short* tp = &tile[r * 72 + cs];
#pragma unroll
    for (int i = 0; i < 4; ++i) {
      float4 v = sp[i];
      tp[i * 4 + 0] = f2bf(v.x); tp[i * 4 + 1] = f2bf(v.y);
      tp[i * 4 + 2] = f2bf(v.z); tp[i * 4 + 3] = f2bf(v.w);
    }
  }
  __syncthreads();
  {
    int n = tid >> 2, ks = (tid & 3) * 16;  // dst row n0+n, 16 k's
    unsigned short buf[16];
#pragma unroll
    for (int e = 0; e < 16; ++e) buf[e] = tile[(ks + e) * 72 + n];
    unsigned short* dp = dst + (size_t)(n0 + n) * Kd + k0 + ks;
    *(short8*)dp = *(const short8*)&buf[0];
    *(short8*)(dp + 8) = *(const short8*)&buf[8];
  }
}

// ---------------- V transpose: QKVb V-cols -> Vg[b][h][d][key] ----------------
// 64key x 64d tiles through LDS; coalesced read and write. Grid 1024.
__global__ __launch_bounds__(256)
void k_vt(const unsigned short* __restrict__ QKV, unsigned short* __restrict__ Vg) {
  __shared__ unsigned short tile[64 * 72];
  const int t = blockIdx.x;
  const int kt = t & 63, h = (t >> 6) & 7, b = t >> 9;
  const int tid = threadIdx.x;
  {
    int r = tid >> 2, cs = (tid & 3) * 16;  // key row kt*64+r, d-cols cs..cs+16
    const unsigned short* sp = QKV + (size_t)(b * L + kt * 64 + r) * 1536 + 1024 + h * 64 + cs;
    unsigned short* tp = &tile[r * 72 + cs];
    *(short8*)tp = *(const short8*)sp;
    *(short8*)(tp + 8) = *(const short8*)(sp + 8);
  }
  __syncthreads();
  {
    int d = tid >> 2, ks = (tid & 3) * 16;  // d-row, 16 keys
    unsigned short buf[16];
#pragma unroll
    for (int e = 0; e < 16; ++e) buf[e] = tile[(ks + e) * 72 + d];
    unsigned short* dp = Vg + ((size_t)(b * 8 + h) * 64 + d) * L + kt * 64 + ks;
    *(short8*)dp = *(const short8*)&buf[0];
    *(short8*)(dp + 8) = *(const short8*)&buf[8];
  }
}

// ---------------- bf16 MFMA GEMM (m97 structure): C = A @ BT^T + bias --------
template <int EPI>
__global__ __launch_bounds__(256, 3)
void k_gemm(const unsigned short* __restrict__ A, const unsigned short* __restrict__ BT,
            const float* __restrict__ bias, void* __restrict__ Cout,
            const int klen, const int N) {
  __shared__ unsigned short lA[128 * 32];
  __shared__ unsigned short lB[128 * 32];
  const int tid = threadIdx.x;
  const int wave = tid >> 6, lane = tid & 63;
  const int quad = lane >> 4, l16 = lane & 15;
  const int m0 = blockIdx.y * 128, n0 = blockIdx.x * 128;
  const int wm = (wave >> 1) * 64, wn = (wave & 1) * 64;
  const int kbeg = blockIdx.z * klen;
  const size_t Kdim = (size_t)klen * gridDim.z;

  const floatx4 fzero = {0.f, 0.f, 0.f, 0.f};
  floatx4 acc[4][4];
#pragma unroll
  for (int i = 0; i < 4; ++i)
#pragma unroll
    for (int j = 0; j < 4; ++j) acc[i][j] = fzero;

  const int r0 = tid >> 2, o0 = (tid & 3) * 8;
  const int r1 = (256 + tid) >> 2, o1 = (tid & 3) * 8;
  const unsigned short* Ag0 = A + (size_t)(m0 + r0) * Kdim + kbeg + o0;
  const unsigned short* Ag1 = A + (size_t)(m0 + r1) * Kdim + kbeg + o1;
  const unsigned short* Bg0 = BT + (size_t)(n0 + r0) * Kdim + kbeg + o0;
  const unsigned short* Bg1 = BT + (size_t)(n0 + r1) * Kdim + kbeg + o1;
  unsigned short* lA0 = &lA[wave * 512];
  unsigned short* lA1 = &lA[(4 + wave) * 512];
  unsigned short* lB0 = &lB[wave * 512];
  unsigned short* lB1 = &lB[(4 + wave) * 512];

  for (int kt = 0; kt < klen; kt += 32) {
    __syncthreads();
    gl_lds16(Ag0 + kt, lA0);
    gl_lds16(Ag1 + kt, lA1);
    gl_lds16(Bg0 + kt, lB0);
    gl_lds16(Bg1 + kt, lB1);
    __syncthreads();
    short8 af[4], bf[4];
#pragma unroll
    for (int i = 0; i < 4; ++i) af[i] = *(const short8*)&lA[(wm + i * 16 + l16) * 32 + quad * 8];
#pragma unroll
    for (int j = 0; j < 4; ++j) bf[j] = *(const short8*)&lB[(wn + j * 16 + l16) * 32 + quad * 8];
#pragma unroll
    for (int i = 0; i < 4; ++i)
#pragma unroll
      for (int j = 0; j < 4; ++j)
        acc[i][j] = __builtin_amdgcn_mfma_f32_16x16x32_bf16(af[i], bf[j], acc[i][j], 0, 0, 0);
  }

  float* outf = (float*)Cout + (size_t)blockIdx.z * M * N;
#pragma unroll
  for (int j = 0; j < 4; ++j) {
    const int col = n0 + wn + j * 16 + l16;
    const float bv = (blockIdx.z == 0) ? bias[col] : 0.f;
#pragma unroll
    for (int i = 0; i < 4; ++i) {
      const int row = m0 + wm + i * 16 + quad * 4;
#pragma unroll
      for (int r = 0; r < 4; ++r) {
        float v = acc[i][j][r] + bv;
        if (EPI == 1) v = fmaxf(v, 0.f);
        if (EPI == 2)
          outf[(size_t)(row + r) * N + col] = v;
        else
          ((unsigned short*)Cout)[(size_t)(row + r) * N + col] = f2bf(v);
      }
    }
  }
}

// ---------------- banded flash attention (v6) ---------------------------------
// No V staging in LDS: V pre-transposed to Vg[b][h][d][key], PV B-fragments
// read directly from global as dwordx4 (16 full 64B lines per instr). LDS =
// per-wave P buffer only (9 KB) -> 4 blocks/CU, 16 waves/CU, single grid pass,
// zero __syncthreads. qt-fastest order; softmax-free (s bounded + shift
// invariance). jbg is a multiple of 64, so every 8-key V vector is entirely
// masked (P=0, clamped load OK) or entirely valid.
__global__ __launch_bounds__(256, 4)
void k_attn(const unsigned short* __restrict__ QKV, const unsigned short* __restrict__ Vg,
            unsigned short* __restrict__ attnb, const int* __restrict__ wptr) {
  const int W = wptr[0];  // 128
  __shared__ unsigned short Pb[4][16 * 72];  // 9216 B
  const int tid = threadIdx.x;
  const int wave = tid >> 6, lane = tid & 63;
  const int quad = lane >> 4, l16 = lane & 15;
  const int blk = blockIdx.x;
  const int qt = blk & 63, h = (blk >> 6) & 7, b = blk >> 9;  // qt fastest
  const int q0blk = qt * 64;
  const int q0 = q0blk + wave * 16;
  const float scale = 0.125f;  // 1/sqrt(64)

  const unsigned short* Kbase = QKV + (size_t)(b * L) * 1536 + 512 + h * 64;
  const unsigned short* Vh = Vg + (size_t)(b * 8 + h) * 64 * L;  // [d][key]

  const unsigned short* Qp = QKV + (size_t)(b * L + q0 + l16) * 1536 + h * 64;
  short8 qf0 = *(const short8*)(Qp + quad * 8);
  short8 qf1 = *(const short8*)(Qp + 32 + quad * 8);

  const floatx4 fzero = {0.f, 0.f, 0.f, 0.f};
  floatx4 o[4];
#pragma unroll
  for (int i = 0; i < 4; ++i) o[i] = fzero;
  float lsum[4] = {0.f, 0.f, 0.f, 0.f};
  unsigned short* lp = Pb[wave];

  for (int it = 0; it < 5; ++it) {  // 5 x 64-key tiles cover the 320-key band
    const int jbg = q0blk - 128 + it * 64;
    floatx4 s[4];
#pragma unroll
    for (int ct = 0; ct < 4; ++ct) {
      int key = jbg + ct * 16 + l16;
      int keyc = key < 0 ? 0 : (key > L - 1 ? L - 1 : key);
      const unsigned short* Kr = Kbase + (size_t)keyc * 1536;
      floatx4 z = fzero;
      z = __builtin_amdgcn_mfma_f32_16x16x32_bf16(qf0, *(const short8*)(Kr + quad * 8), z, 0, 0, 0);
      z = __builtin_amdgcn_mfma_f32_16x16x32_bf16(qf1, *(const short8*)(Kr + 32 + quad * 8), z, 0, 0, 0);
      s[ct] = z;
    }
#pragma unroll
    for (int r = 0; r < 4; ++r) {
      int q = q0 + quad * 4 + r;
#pragma unroll
      for (int ct = 0; ct < 4; ++ct) {
        int key = jbg + ct * 16 + l16;
        int d = q - key; d = d < 0 ? -d : d;
        bool ok = (key >= 0) && (key < L) && (d <= W);
        float p = ok ? __expf(s[ct][r] * scale) : 0.f;  // fixed m=0, masked to 0
        lsum[r] += p;
        lp[(quad * 4 + r) * 72 + ct * 16 + l16] = f2bf(p);
      }
    }
    // PV: A = P (16q x 64key) from LDS, B = V (64key x 64d) from global Vg
    short8 pf0 = *(const short8*)&lp[l16 * 72 + quad * 8];
    short8 pf1 = *(const short8*)&lp[l16 * 72 + 32 + quad * 8];
    int kb0 = jbg + quad * 8;       kb0 = kb0 < 0 ? 0 : (kb0 > L - 8 ? L - 8 : kb0);
    int kb1 = jbg + 32 + quad * 8;  kb1 = kb1 < 0 ? 0 : (kb1 > L - 8 ? L - 8 : kb1);
#pragma unroll
    for (int nt = 0; nt < 4; ++nt) {
      const unsigned short* vrow = Vh + (size_t)(nt * 16 + l16) * L;
      short8 vf0 = *(const short8*)(vrow + kb0);
      short8 vf1 = *(const short8*)(vrow + kb1);
      o[nt] = __builtin_amdgcn_mfma_f32_16x16x32_bf16(pf0, vf0, o[nt], 0, 0, 0);
      o[nt] = __builtin_amdgcn_mfma_f32_16x16x32_bf16(pf1, vf1, o[nt], 0, 0, 0);
    }
  }
  // single final reduction of l over the 16 key-lanes
#pragma unroll
  for (int r = 0; r < 4; ++r) {
#pragma unroll
    for (int dd = 1; dd < 16; dd <<= 1) lsum[r] += __shfl_xor(lsum[r], dd, 64);
  }
#pragma unroll
  for (int r = 0; r < 4; ++r) {
    float inv = 1.f / lsum[r];
    size_t base = (size_t)(b * L + q0 + quad * 4 + r) * 512 + h * 64;
#pragma unroll
    for (int nt = 0; nt < 4; ++nt)
      attnb[base + nt * 16 + l16] = f2bf(o[nt][r] * inv);
  }
}

// ---------------- fused residual + LayerNorm ----------------------------------
template <int NP>
__global__ __launch_bounds__(256, 2)
void k_res_ln(const float* __restrict__ t0, const float* __restrict__ t1,
              const float* __restrict__ res,
              const float* __restrict__ gamma, const float* __restrict__ beta,
              float* __restrict__ outf, unsigned short* __restrict__ outb) {
  const int wave = threadIdx.x >> 6, lane = threadIdx.x & 63;
  const int row = blockIdx.x * 4 + wave;
  const float4* tv = (const float4*)(t0 + (size_t)row * D);
  const float4* rv = (const float4*)(res + (size_t)row * D);
  float4 a0 = tv[lane], a1 = tv[lane + 64];
  float4 b0 = rv[lane], b1 = rv[lane + 64];
  float4 y0 = make_float4(a0.x + b0.x, a0.y + b0.y, a0.z + b0.z, a0.w + b0.w);
  float4 y1 = make_float4(a1.x + b1.x, a1.y + b1.y, a1.z + b1.z, a1.w + b1.w);
  if (NP == 2) {
    const float4* uv = (const float4*)(t1 + (size_t)row * D);
    float4 c0 = uv[lane], c1 = uv[lane + 64];
    y0.x += c0.x; y0.y += c0.y; y0.z += c0.z; y0.w += c0.w;
    y1.x += c1.x; y1.y += c1.y; y1.z += c1.z; y1.w += c1.w;
  }
  float s = y0.x + y0.y + y0.z + y0.w + y1.x + y1.y + y1.z + y1.w;
  float q = y0.x * y0.x + y0.y * y0.y + y0.z * y0.z + y0.w * y0.w +
            y1.x * y1.x + y1.y * y1.y + y1.z * y1.z + y1.w * y1.w;
#pragma unroll
  for (int d = 1; d < 64; d <<= 1) {
    s += __shfl_xor(s, d, 64);
    q += __shfl_xor(q, d, 64);
  }
  const float mean = s * (1.f / D);
  const float var = q * (1.f / D) - mean * mean;
  const float rstd = rsqrtf(var + LN_EPS);
  float4 g0 = ((const float4*)gamma)[lane], g1 = ((const float4*)gamma)[lane + 64];
  float4 e0 = ((const float4*)beta)[lane], e1 = ((const float4*)beta)[lane + 64];
  float4 o0 = make_float4((y0.x - mean) * rstd * g0.x + e0.x, (y0.y - mean) * rstd * g0.y + e0.y,
                          (y0.z - mean) * rstd * g0.z + e0.z, (y0.w - mean) * rstd * g0.w + e0.w);
  float4 o1 = make_float4((y1.x - mean) * rstd * g1.x + e1.x, (y1.y - mean) * rstd * g1.y + e1.y,
                          (y1.z - mean) * rstd * g1.z + e1.z, (y1.w - mean) * rstd * g1.w + e1.w);
  ((float4*)(outf + (size_t)row * D))[lane] = o0;
  ((float4*)(outf + (size_t)row * D))[lane + 64] = o1;
  if (outb) {
    ((ushort4*)(outb + (size_t)row * D))[lane] =
        make_ushort4(f2bf(o0.x), f2bf(o0.y), f2bf(o0.z), f2bf(o0.w));
    ((ushort4*)(outb + (size_t)row * D))[lane + 64] =
        make_ushort4(f2bf(o1.x), f2bf(o1.y), f2bf(o1.z), f2bf(o1.w));
  }
}

}  // namespace

extern "C" void kernel_launch(void* const* d_in, const int* in_sizes, int n_in,
                              void* d_out, int out_size, void* d_ws, size_t ws_size,
                              hipStream_t stream) {
  const float* x   = (const float*)d_in[0];
  const float* Wq  = (const float*)d_in[1];
  const float* bq  = (const float*)d_in[2];
  const float* Wk  = (const float*)d_in[3];
  const float* bk  = (const float*)d_in[4];
  const float* Wv  = (const float*)d_in[5];
  const float* bv  = (const float*)d_in[6];
  const float* Wo  = (const float*)d_in[7];
  const float* bo  = (const float*)d_in[8];
  const float* g1  = (const float*)d_in[9];
  const float* be1 = (const float*)d_in[10];
  const float* W1  = (const float*)d_in[11];
  const float* b1  = (const float*)d_in[12];
  const float* W2  = (const float*)d_in[13];
  const float* b2  = (const float*)d_in[14];
  const float* g2  = (const float*)d_in[15];
  const float* be2 = (const float*)d_in[16];
  const int* wptr  = (const int*)d_in[17];
  float* out = (float*)d_out;

  char* w = (char*)d_ws;
  size_t off = 0;
  auto take = [&](size_t bytes) -> void* {
    void* p = w + off;
    off += (bytes + 255) & ~(size_t)255;
    return p;
  };
  unsigned short* Xb    = (unsigned short*)take((size_t)M * D * 2);      // 8 MiB
  unsigned short* QKVb  = (unsigned short*)take((size_t)M * 1536 * 2);   // 24 MiB
  unsigned short* attnb = (unsigned short*)take((size_t)M * D * 2);      // 8 MiB
  unsigned short* Vg    = (unsigned short*)take((size_t)M * D * 2);      // 8 MiB (V^T per head)
  unsigned short* WqkvT = (unsigned short*)take((size_t)1536 * 512 * 2); // 1.5 MiB
  unsigned short* WoT   = (unsigned short*)take((size_t)512 * 512 * 2);  // 0.5 MiB
  unsigned short* W1T   = (unsigned short*)take((size_t)2048 * 512 * 2); // 2 MiB
  unsigned short* W2T   = (unsigned short*)take((size_t)512 * 2048 * 2); // 2 MiB
  float* bqkv           = (float*)take(1536 * 4);
  float* tbuf           = (float*)take((size_t)2 * M * D * 4);           // 32 MiB (2 split-K partials)
  float* hbuf           = (float*)take((size_t)M * D * 4);               // 16 MiB
  unsigned short* hb    = (unsigned short*)take((size_t)M * D * 2);      // 8 MiB
  unsigned short* ffb   = (unsigned short*)take((size_t)M * FF * 2);     // 32 MiB

  k_prep<<<4870, 256, 0, stream>>>(x, Wq, Wk, Wv, Wo, W1, W2, bq, bk, bv,
                                   Xb, WqkvT, WoT, W1T, W2T, bqkv);
  k_gemm<0><<<dim3(12, 64, 1), 256, 0, stream>>>(Xb, WqkvT, bqkv, QKVb, 512, 1536);
  k_vt<<<1024, 256, 0, stream>>>(QKVb, Vg);
  k_attn<<<B * H * (L / 64), 256, 0, stream>>>(QKVb, Vg, attnb, wptr);
  k_gemm<2><<<dim3(4, 64, 2), 256, 0, stream>>>(attnb, WoT, bo, tbuf, 256, 512);
  k_res_ln<2><<<M / 4, 256, 0, stream>>>(tbuf, tbuf + (size_t)M * D, x, g1, be1, hbuf, hb);
  k_gemm<1><<<dim3(16, 64, 1), 256, 0, stream>>>(hb, W1T, b1, ffb, 512, 2048);
  k_gemm<2><<<dim3(4, 64, 2), 256, 0, stream>>>(ffb, W2T, b2, tbuf, 1024, 512);
  k_res_ln<2><<<M / 4, 256, 0, stream>>>(tbuf, tbuf + (size_t)M * D, hbuf, g2, be2, out, nullptr);
}

// Round 9
// 256.391 us; speedup vs baseline: 1.0707x; 1.0707x over previous
//
#include <hip/hip_runtime.h>

namespace {

constexpr int B = 2, L = 4096, D = 512, H = 8, FF = 2048;
constexpr int M = B * L; // 8192
constexpr float LN_EPS = 1e-5f;

typedef __attribute__((ext_vector_type(8))) short short8;
typedef __attribute__((ext_vector_type(4))) float floatx4;

typedef __attribute__((address_space(3))) unsigned int lds_uint;
typedef const __attribute__((address_space(1))) unsigned int glob_uint;

__device__ __forceinline__ void gl_lds16(const unsigned short* g, unsigned short* l) {
  // async global->LDS, 16B/lane; LDS dest = wave-uniform base + lane*16 (m104)
  __builtin_amdgcn_global_load_lds((glob_uint*)g, (lds_uint*)l, 16, 0, 0);
}

__device__ __forceinline__ unsigned short f2bf(float f) {
  union { float f; unsigned u; } v; v.f = f;
  unsigned r = v.u + 0x7FFFu + ((v.u >> 16) & 1u);
  return (unsigned short)(r >> 16);
}

// ---------------- fused prep: x->bf16 + bias concat + weight transposes ------
__global__ __launch_bounds__(256)
void k_prep(const float* __restrict__ x,
            const float* __restrict__ Wq, const float* __restrict__ Wk,
            const float* __restrict__ Wv, const float* __restrict__ Wo,
            const float* __restrict__ W1, const float* __restrict__ W2,
            const float* __restrict__ bq, const float* __restrict__ bk,
            const float* __restrict__ bv,
            unsigned short* __restrict__ Xb,
            unsigned short* __restrict__ WqkvT, unsigned short* __restrict__ WoT,
            unsigned short* __restrict__ W1T, unsigned short* __restrict__ W2T,
            float* __restrict__ bqkv) {
  __shared__ unsigned short tile[64 * 72];
  if (blockIdx.x < 4102) {
    int tid = blockIdx.x * blockDim.x + threadIdx.x;
    if (tid < 1048576) {  // x: 4 elems per thread (M*D = 4194304)
      float4 v = ((const float4*)x)[tid];
      ((ushort4*)Xb)[tid] = make_ushort4(f2bf(v.x), f2bf(v.y), f2bf(v.z), f2bf(v.w));
      return;
    }
    int u = tid - 1048576;
    if (u < 1536) bqkv[u] = (u < 512) ? bq[u] : (u < 1024 ? bk[u - 512] : bv[u - 1024]);
    return;
  }
  const int t = blockIdx.x - 4102;
  const float* src; unsigned short* dst; int Ns, Kd, n0, k0, nsrc0;
  if (t < 192) {        // WqkvT [1536][512] from Wq/Wk/Wv [512][512]
    int nt = t % 24, kt = t / 24; int ng = nt * 64;
    src = ng < 512 ? Wq : (ng < 1024 ? Wk : Wv);
    Ns = 512; Kd = 512; n0 = ng; nsrc0 = ng & 511; k0 = kt * 64; dst = WqkvT;
  } else if (t < 256) { // WoT [512][512] from Wo [512][512]
    int u = t - 192; int nt = u % 8, kt = u / 8;
    src = Wo; Ns = 512; Kd = 512; n0 = nt * 64; nsrc0 = n0; k0 = kt * 64; dst = WoT;
  } else if (t < 512) { // W1T [2048][512] from W1 [512][2048]
    int u = t - 256; int nt = u % 32, kt = u / 32;
    src = W1; Ns = 2048; Kd = 512; n0 = nt * 64; nsrc0 = n0; k0 = kt * 64; dst = W1T;
  } else {              // W2T [512][2048] from W2 [2048][512]
    int u = t - 512; int nt = u % 8, kt = u / 8;
    src = W2; Ns = 512; Kd = 2048; n0 = nt * 64; nsrc0 = n0; k0 = kt * 64; dst = W2T;
  }
  const int tid = threadIdx.x;
  {
    int r = tid >> 2, cs = (tid & 3) * 16;  // src row k0+r, 16 cols
    const float4* sp = (const float4*)(src + (size_t)(k0 + r) * Ns + nsrc0 + cs);
    unsigned short* tp = &tile[r * 72 + cs];
#pragma unroll
    for (int i = 0; i < 4; ++i) {
      float4 v = sp[i];
      tp[i * 4 + 0] = f2bf(v.x); tp[i * 4 + 1] = f2bf(v.y);
      tp[i * 4 + 2] = f2bf(v.z); tp[i * 4 + 3] = f2bf(v.w);
    }
  }
  __syncthreads();
  {
    int n = tid >> 2, ks = (tid & 3) * 16;  // dst row n0+n, 16 k's
    unsigned short buf[16];
#pragma unroll
    for (int e = 0; e < 16; ++e) buf[e] = tile[(ks + e) * 72 + n];
    unsigned short* dp = dst + (size_t)(n0 + n) * Kd + k0 + ks;
    *(short8*)dp = *(const short8*)&buf[0];
    *(short8*)(dp + 8) = *(const short8*)&buf[8];
  }
}

// ---------------- V transpose: QKVb V-cols -> Vg[b][h][d][key] ----------------
__global__ __launch_bounds__(256)
void k_vt(const unsigned short* __restrict__ QKV, unsigned short* __restrict__ Vg) {
  __shared__ unsigned short tile[64 * 72];
  const int t = blockIdx.x;
  const int kt = t & 63, h = (t >> 6) & 7, b = t >> 9;
  const int tid = threadIdx.x;
  {
    int r = tid >> 2, cs = (tid & 3) * 16;
    const unsigned short* sp = QKV + (size_t)(b * L + kt * 64 + r) * 1536 + 1024 + h * 64 + cs;
    unsigned short* tp = &tile[r * 72 + cs];
    *(short8*)tp = *(const short8*)sp;
    *(short8*)(tp + 8) = *(const short8*)(sp + 8);
  }
  __syncthreads();
  {
    int d = tid >> 2, ks = (tid & 3) * 16;
    unsigned short buf[16];
#pragma unroll
    for (int e = 0; e < 16; ++e) buf[e] = tile[(ks + e) * 72 + d];
    unsigned short* dp = Vg + ((size_t)(b * 8 + h) * 64 + d) * L + kt * 64 + ks;
    *(short8*)dp = *(const short8*)&buf[0];
    *(short8*)(dp + 8) = *(const short8*)&buf[8];
  }
}

// ---------------- bf16 MFMA GEMM (m97 structure): C = A @ BT^T + bias --------
template <int EPI>
__global__ __launch_bounds__(256, 3)
void k_gemm(const unsigned short* __restrict__ A, const unsigned short* __restrict__ BT,
            const float* __restrict__ bias, void* __restrict__ Cout,
            const int klen, const int N) {
  __shared__ unsigned short lA[128 * 32];
  __shared__ unsigned short lB[128 * 32];
  const int tid = threadIdx.x;
  const int wave = tid >> 6, lane = tid & 63;
  const int quad = lane >> 4, l16 = lane & 15;
  const int m0 = blockIdx.y * 128, n0 = blockIdx.x * 128;
  const int wm = (wave >> 1) * 64, wn = (wave & 1) * 64;
  const int kbeg = blockIdx.z * klen;
  const size_t Kdim = (size_t)klen * gridDim.z;

  const floatx4 fzero = {0.f, 0.f, 0.f, 0.f};
  floatx4 acc[4][4];
#pragma unroll
  for (int i = 0; i < 4; ++i)
#pragma unroll
    for (int j = 0; j < 4; ++j) acc[i][j] = fzero;

  const int r0 = tid >> 2, o0 = (tid & 3) * 8;
  const int r1 = (256 + tid) >> 2, o1 = (tid & 3) * 8;
  const unsigned short* Ag0 = A + (size_t)(m0 + r0) * Kdim + kbeg + o0;
  const unsigned short* Ag1 = A + (size_t)(m0 + r1) * Kdim + kbeg + o1;
  const unsigned short* Bg0 = BT + (size_t)(n0 + r0) * Kdim + kbeg + o0;
  const unsigned short* Bg1 = BT + (size_t)(n0 + r1) * Kdim + kbeg + o1;
  unsigned short* lA0 = &lA[wave * 512];
  unsigned short* lA1 = &lA[(4 + wave) * 512];
  unsigned short* lB0 = &lB[wave * 512];
  unsigned short* lB1 = &lB[(4 + wave) * 512];

  for (int kt = 0; kt < klen; kt += 32) {
    __syncthreads();
    gl_lds16(Ag0 + kt, lA0);
    gl_lds16(Ag1 + kt, lA1);
    gl_lds16(Bg0 + kt, lB0);
    gl_lds16(Bg1 + kt, lB1);
    __syncthreads();
    short8 af[4], bf[4];
#pragma unroll
    for (int i = 0; i < 4; ++i) af[i] = *(const short8*)&lA[(wm + i * 16 + l16) * 32 + quad * 8];
#pragma unroll
    for (int j = 0; j < 4; ++j) bf[j] = *(const short8*)&lB[(wn + j * 16 + l16) * 32 + quad * 8];
#pragma unroll
    for (int i = 0; i < 4; ++i)
#pragma unroll
      for (int j = 0; j < 4; ++j)
        acc[i][j] = __builtin_amdgcn_mfma_f32_16x16x32_bf16(af[i], bf[j], acc[i][j], 0, 0, 0);
  }

  float* outf = (float*)Cout + (size_t)blockIdx.z * M * N;
#pragma unroll
  for (int j = 0; j < 4; ++j) {
    const int col = n0 + wn + j * 16 + l16;
    const float bv = (blockIdx.z == 0) ? bias[col] : 0.f;
#pragma unroll
    for (int i = 0; i < 4; ++i) {
      const int row = m0 + wm + i * 16 + quad * 4;
#pragma unroll
      for (int r = 0; r < 4; ++r) {
        float v = acc[i][j][r] + bv;
        if (EPI == 1) v = fmaxf(v, 0.f);
        if (EPI == 2)
          outf[(size_t)(row + r) * N + col] = v;
        else
          ((unsigned short*)Cout)[(size_t)(row + r) * N + col] = f2bf(v);
      }
    }
  }
}

// ---------------- banded flash attention (v7) ---------------------------------
// Double-buffered global_load_lds DMA staging of K and V tiles (zero VGPR
// pipeline cost -- round-7's register prefetch spilled). Tile it+1's DMA is
// issued at the top of iter it; one __syncthreads per iter (vmcnt drain =
// pipeline wait). K/V tiles loaded ONCE per block (was 4x redundant per-wave).
// LDS chunk XOR-swizzle: chunk(key,dpart) at index key*8 + (dpart^(key&7)) --
// DMA stays lane-contiguous, ds_read_b128 fragment reads hit every bank
// exactly 8x (uniform). Softmax-free (s bounded + shift-invariance);
// qt-fastest order; P per-wave (same-wave LDS RAW via lgkmcnt).
__global__ __launch_bounds__(256, 3)
void k_attn(const unsigned short* __restrict__ QKV, const unsigned short* __restrict__ Vg,
            unsigned short* __restrict__ attnb, const int* __restrict__ wptr) {
  const int W = wptr[0];  // 128
  __shared__ unsigned short Kt[2][4096];     // 64key x 64d tiles, swizzled (8 KB ea)
  __shared__ unsigned short Vt[2][4096];     // 64d x 64key tiles, swizzled
  __shared__ unsigned short Pb[4][16 * 72];  // 9216 B
  const int tid = threadIdx.x;
  const int wave = tid >> 6, lane = tid & 63;
  const int quad = lane >> 4, l16 = lane & 15;
  const int blk = blockIdx.x;
  const int qt = blk & 63, h = (blk >> 6) & 7, b = blk >> 9;  // qt fastest
  const int q0blk = qt * 64;
  const int q0 = q0blk + wave * 16;
  const float scale = 0.125f;  // 1/sqrt(64)

  const unsigned short* Kbase = QKV + (size_t)(b * L) * 1536 + 512 + h * 64;
  const unsigned short* Vh = Vg + (size_t)(b * 8 + h) * 64 * L;  // [d][key]

  // DMA one 64-key tile (K and V) into buffer `buf`. 512 chunks each.
  auto stage = [&](int buf, int jbg) {
#pragma unroll
    for (int i = 0; i < 2; ++i) {
      int c = i * 256 + tid;                       // chunk index
      int key = jbg + (c >> 3);
      int keyc = key < 0 ? 0 : (key > L - 1 ? L - 1 : key);  // P=0 there
      int dpart = (c & 7) ^ ((c >> 3) & 7);        // XOR swizzle
      gl_lds16(Kbase + (size_t)keyc * 1536 + dpart * 8,
               &Kt[buf][(i * 256 + wave * 64) * 8]);
    }
#pragma unroll
    for (int i = 0; i < 2; ++i) {
      int c = i * 256 + tid;
      int d = c >> 3;
      int kpart = (c & 7) ^ (d & 7);
      int kb = jbg + kpart * 8;
      kb = kb < 0 ? 0 : (kb > L - 8 ? L - 8 : kb);  // 8-aligned, P=0 where invalid
      gl_lds16(Vh + (size_t)d * L + kb,
               &Vt[buf][(i * 256 + wave * 64) * 8]);
    }
  };

  const unsigned short* Qp = QKV + (size_t)(b * L + q0 + l16) * 1536 + h * 64;
  short8 qf0 = *(const short8*)(Qp + quad * 8);
  short8 qf1 = *(const short8*)(Qp + 32 + quad * 8);

  const floatx4 fzero = {0.f, 0.f, 0.f, 0.f};
  floatx4 o[4];
#pragma unroll
  for (int i = 0; i < 4; ++i) o[i] = fzero;
  float lsum[4] = {0.f, 0.f, 0.f, 0.f};
  unsigned short* lp = Pb[wave];
  const int sw = l16 & 7;  // swizzle term for fragment reads

  stage(0, q0blk - 128);
  __syncthreads();

  for (int it = 0; it < 5; ++it) {  // 5 x 64-key tiles cover the 320-key band
    const int jbg = q0blk - 128 + it * 64;
    if (it < 4) stage((it + 1) & 1, jbg + 64);  // prefetch next tile (async DMA)
    const unsigned short* lk = Kt[it & 1];
    const unsigned short* lv = Vt[it & 1];
    // QK^T from LDS K tile
    floatx4 s[4];
#pragma unroll
    for (int ct = 0; ct < 4; ++ct) {
      int key = ct * 16 + l16;
      const short8 kf0 = *(const short8*)&lk[(key * 8 + (quad ^ sw)) * 8];
      const short8 kf1 = *(const short8*)&lk[(key * 8 + ((quad + 4) ^ sw)) * 8];
      floatx4 z = fzero;
      z = __builtin_amdgcn_mfma_f32_16x16x32_bf16(qf0, kf0, z, 0, 0, 0);
      z = __builtin_amdgcn_mfma_f32_16x16x32_bf16(qf1, kf1, z, 0, 0, 0);
      s[ct] = z;
    }
#pragma unroll
    for (int r = 0; r < 4; ++r) {
      int q = q0 + quad * 4 + r;
#pragma unroll
      for (int ct = 0; ct < 4; ++ct) {
        int key = jbg + ct * 16 + l16;
        int d = q - key; d = d < 0 ? -d : d;
        bool ok = (key >= 0) && (key < L) && (d <= W);
        float p = ok ? __expf(s[ct][r] * scale) : 0.f;  // fixed m=0, masked to 0
        lsum[r] += p;
        lp[(quad * 4 + r) * 72 + ct * 16 + l16] = f2bf(p);
      }
    }
    // PV: A = P (16q x 64key) from LDS, B = V^T tile from LDS
    short8 pf0 = *(const short8*)&lp[l16 * 72 + quad * 8];
    short8 pf1 = *(const short8*)&lp[l16 * 72 + 32 + quad * 8];
#pragma unroll
    for (int nt = 0; nt < 4; ++nt) {
      int d = nt * 16 + l16;
      const short8 vf0 = *(const short8*)&lv[(d * 8 + (quad ^ sw)) * 8];
      const short8 vf1 = *(const short8*)&lv[(d * 8 + ((quad + 4) ^ sw)) * 8];
      o[nt] = __builtin_amdgcn_mfma_f32_16x16x32_bf16(pf0, vf0, o[nt], 0, 0, 0);
      o[nt] = __builtin_amdgcn_mfma_f32_16x16x32_bf16(pf1, vf1, o[nt], 0, 0, 0);
    }
    __syncthreads();  // drains next-tile DMA + guards buffer reuse
  }
  // single final reduction of l over the 16 key-lanes
#pragma unroll
  for (int r = 0; r < 4; ++r) {
#pragma unroll
    for (int dd = 1; dd < 16; dd <<= 1) lsum[r] += __shfl_xor(lsum[r], dd, 64);
  }
#pragma unroll
  for (int r = 0; r < 4; ++r) {
    float inv = 1.f / lsum[r];
    size_t base = (size_t)(b * L + q0 + quad * 4 + r) * 512 + h * 64;
#pragma unroll
    for (int nt = 0; nt < 4; ++nt)
      attnb[base + nt * 16 + l16] = f2bf(o[nt][r] * inv);
  }
}

// ---------------- fused residual + LayerNorm ----------------------------------
template <int NP>
__global__ __launch_bounds__(256, 2)
void k_res_ln(const float* __restrict__ t0, const float* __restrict__ t1,
              const float* __restrict__ res,
              const float* __restrict__ gamma, const float* __restrict__ beta,
              float* __restrict__ outf, unsigned short* __restrict__ outb) {
  const int wave = threadIdx.x >> 6, lane = threadIdx.x & 63;
  const int row = blockIdx.x * 4 + wave;
  const float4* tv = (const float4*)(t0 + (size_t)row * D);
  const float4* rv = (const float4*)(res + (size_t)row * D);
  float4 a0 = tv[lane], a1 = tv[lane + 64];
  float4 b0 = rv[lane], b1 = rv[lane + 64];
  float4 y0 = make_float4(a0.x + b0.x, a0.y + b0.y, a0.z + b0.z, a0.w + b0.w);
  float4 y1 = make_float4(a1.x + b1.x, a1.y + b1.y, a1.z + b1.z, a1.w + b1.w);
  if (NP == 2) {
    const float4* uv = (const float4*)(t1 + (size_t)row * D);
    float4 c0 = uv[lane], c1 = uv[lane + 64];
    y0.x += c0.x; y0.y += c0.y; y0.z += c0.z; y0.w += c0.w;
    y1.x += c1.x; y1.y += c1.y; y1.z += c1.z; y1.w += c1.w;
  }
  float s = y0.x + y0.y + y0.z + y0.w + y1.x + y1.y + y1.z + y1.w;
  float q = y0.x * y0.x + y0.y * y0.y + y0.z * y0.z + y0.w * y0.w +
            y1.x * y1.x + y1.y * y1.y + y1.z * y1.z + y1.w * y1.w;
#pragma unroll
  for (int d = 1; d < 64; d <<= 1) {
    s += __shfl_xor(s, d, 64);
    q += __shfl_xor(q, d, 64);
  }
  const float mean = s * (1.f / D);
  const float var = q * (1.f / D) - mean * mean;
  const float rstd = rsqrtf(var + LN_EPS);
  float4 g0 = ((const float4*)gamma)[lane], g1 = ((const float4*)gamma)[lane + 64];
  float4 e0 = ((const float4*)beta)[lane], e1 = ((const float4*)beta)[lane + 64];
  float4 o0 = make_float4((y0.x - mean) * rstd * g0.x + e0.x, (y0.y - mean) * rstd * g0.y + e0.y,
                          (y0.z - mean) * rstd * g0.z + e0.z, (y0.w - mean) * rstd * g0.w + e0.w);
  float4 o1 = make_float4((y1.x - mean) * rstd * g1.x + e1.x, (y1.y - mean) * rstd * g1.y + e1.y,
                          (y1.z - mean) * rstd * g1.z + e1.z, (y1.w - mean) * rstd * g1.w + e1.w);
  ((float4*)(outf + (size_t)row * D))[lane] = o0;
  ((float4*)(outf + (size_t)row * D))[lane + 64] = o1;
  if (outb) {
    ((ushort4*)(outb + (size_t)row * D))[lane] =
        make_ushort4(f2bf(o0.x), f2bf(o0.y), f2bf(o0.z), f2bf(o0.w));
    ((ushort4*)(outb + (size_t)row * D))[lane + 64] =
        make_ushort4(f2bf(o1.x), f2bf(o1.y), f2bf(o1.z), f2bf(o1.w));
  }
}

}  // namespace

extern "C" void kernel_launch(void* const* d_in, const int* in_sizes, int n_in,
                              void* d_out, int out_size, void* d_ws, size_t ws_size,
                              hipStream_t stream) {
  const float* x   = (const float*)d_in[0];
  const float* Wq  = (const float*)d_in[1];
  const float* bq  = (const float*)d_in[2];
  const float* Wk  = (const float*)d_in[3];
  const float* bk  = (const float*)d_in[4];
  const float* Wv  = (const float*)d_in[5];
  const float* bv  = (const float*)d_in[6];
  const float* Wo  = (const float*)d_in[7];
  const float* bo  = (const float*)d_in[8];
  const float* g1  = (const float*)d_in[9];
  const float* be1 = (const float*)d_in[10];
  const float* W1  = (const float*)d_in[11];
  const float* b1  = (const float*)d_in[12];
  const float* W2  = (const float*)d_in[13];
  const float* b2  = (const float*)d_in[14];
  const float* g2  = (const float*)d_in[15];
  const float* be2 = (const float*)d_in[16];
  const int* wptr  = (const int*)d_in[17];
  float* out = (float*)d_out;

  char* w = (char*)d_ws;
  size_t off = 0;
  auto take = [&](size_t bytes) -> void* {
    void* p = w + off;
    off += (bytes + 255) & ~(size_t)255;
    return p;
  };
  unsigned short* Xb    = (unsigned short*)take((size_t)M * D * 2);      // 8 MiB
  unsigned short* QKVb  = (unsigned short*)take((size_t)M * 1536 * 2);   // 24 MiB
  unsigned short* attnb = (unsigned short*)take((size_t)M * D * 2);      // 8 MiB
  unsigned short* Vg    = (unsigned short*)take((size_t)M * D * 2);      // 8 MiB (V^T per head)
  unsigned short* WqkvT = (unsigned short*)take((size_t)1536 * 512 * 2); // 1.5 MiB
  unsigned short* WoT   = (unsigned short*)take((size_t)512 * 512 * 2);  // 0.5 MiB
  unsigned short* W1T   = (unsigned short*)take((size_t)2048 * 512 * 2); // 2 MiB
  unsigned short* W2T   = (unsigned short*)take((size_t)512 * 2048 * 2); // 2 MiB
  float* bqkv           = (float*)take(1536 * 4);
  float* tbuf           = (float*)take((size_t)2 * M * D * 4);           // 32 MiB (2 split-K partials)
  float* hbuf           = (float*)take((size_t)M * D * 4);               // 16 MiB
  unsigned short* hb    = (unsigned short*)take((size_t)M * D * 2);      // 8 MiB
  unsigned short* ffb   = (unsigned short*)take((size_t)M * FF * 2);     // 32 MiB

  k_prep<<<4870, 256, 0, stream>>>(x, Wq, Wk, Wv, Wo, W1, W2, bq, bk, bv,
                                   Xb, WqkvT, WoT, W1T, W2T, bqkv);
  k_gemm<0><<<dim3(12, 64, 1), 256, 0, stream>>>(Xb, WqkvT, bqkv, QKVb, 512, 1536);
  k_vt<<<1024, 256, 0, stream>>>(QKVb, Vg);
  k_attn<<<B * H * (L / 64), 256, 0, stream>>>(QKVb, Vg, attnb, wptr);
  k_gemm<2><<<dim3(4, 64, 2), 256, 0, stream>>>(attnb, WoT, bo, tbuf, 256, 512);
  k_res_ln<2><<<M / 4, 256, 0, stream>>>(tbuf, tbuf + (size_t)M * D, x, g1, be1, hbuf, hb);
  k_gemm<1><<<dim3(16, 64, 1), 256, 0, stream>>>(hb, W1T, b1, ffb, 512, 2048);
  k_gemm<2><<<dim3(4, 64, 2), 256, 0, stream>>>(ffb, W2T, b2, tbuf, 1024, 512);
  k_res_ln<2><<<M / 4, 256, 0, stream>>>(tbuf, tbuf + (size_t)M * D, hbuf, g2, be2, out, nullptr);
}

// Round 10
// 255.794 us; speedup vs baseline: 1.0732x; 1.0023x over previous
//
#include <hip/hip_runtime.h>

namespace {

constexpr int B = 2, L = 4096, D = 512, H = 8, FF = 2048;
constexpr int M = B * L; // 8192
constexpr float LN_EPS = 1e-5f;

typedef __attribute__((ext_vector_type(8))) short short8;
typedef __attribute__((ext_vector_type(4))) float floatx4;

typedef __attribute__((address_space(3))) unsigned int lds_uint;
typedef const __attribute__((address_space(1))) unsigned int glob_uint;

__device__ __forceinline__ void gl_lds16(const unsigned short* g, unsigned short* l) {
  // async global->LDS, 16B/lane; LDS dest = wave-uniform base + lane*16 (m104)
  __builtin_amdgcn_global_load_lds((glob_uint*)g, (lds_uint*)l, 16, 0, 0);
}

__device__ __forceinline__ unsigned short f2bf(float f) {
  union { float f; unsigned u; } v; v.f = f;
  unsigned r = v.u + 0x7FFFu + ((v.u >> 16) & 1u);
  return (unsigned short)(r >> 16);
}

// ---------------- fused prep: x->bf16 + bias concat + weight transposes ------
__global__ __launch_bounds__(256)
void k_prep(const float* __restrict__ x,
            const float* __restrict__ Wq, const float* __restrict__ Wk,
            const float* __restrict__ Wv, const float* __restrict__ Wo,
            const float* __restrict__ W1, const float* __restrict__ W2,
            const float* __restrict__ bq, const float* __restrict__ bk,
            const float* __restrict__ bv,
            unsigned short* __restrict__ Xb,
            unsigned short* __restrict__ WqkvT, unsigned short* __restrict__ WoT,
            unsigned short* __restrict__ W1T, unsigned short* __restrict__ W2T,
            float* __restrict__ bqkv) {
  __shared__ unsigned short tile[64 * 72];
  if (blockIdx.x < 4102) {
    int tid = blockIdx.x * blockDim.x + threadIdx.x;
    if (tid < 1048576) {  // x: 4 elems per thread (M*D = 4194304)
      float4 v = ((const float4*)x)[tid];
      ((ushort4*)Xb)[tid] = make_ushort4(f2bf(v.x), f2bf(v.y), f2bf(v.z), f2bf(v.w));
      return;
    }
    int u = tid - 1048576;
    if (u < 1536) bqkv[u] = (u < 512) ? bq[u] : (u < 1024 ? bk[u - 512] : bv[u - 1024]);
    return;
  }
  const int t = blockIdx.x - 4102;
  const float* src; unsigned short* dst; int Ns, Kd, n0, k0, nsrc0;
  if (t < 192) {        // WqkvT [1536][512] from Wq/Wk/Wv [512][512]
    int nt = t % 24, kt = t / 24; int ng = nt * 64;
    src = ng < 512 ? Wq : (ng < 1024 ? Wk : Wv);
    Ns = 512; Kd = 512; n0 = ng; nsrc0 = ng & 511; k0 = kt * 64; dst = WqkvT;
  } else if (t < 256) { // WoT [512][512] from Wo [512][512]
    int u = t - 192; int nt = u % 8, kt = u / 8;
    src = Wo; Ns = 512; Kd = 512; n0 = nt * 64; nsrc0 = n0; k0 = kt * 64; dst = WoT;
  } else if (t < 512) { // W1T [2048][512] from W1 [512][2048]
    int u = t - 256; int nt = u % 32, kt = u / 32;
    src = W1; Ns = 2048; Kd = 512; n0 = nt * 64; nsrc0 = n0; k0 = kt * 64; dst = W1T;
  } else {              // W2T [512][2048] from W2 [2048][512]
    int u = t - 512; int nt = u % 8, kt = u / 8;
    src = W2; Ns = 512; Kd = 2048; n0 = nt * 64; nsrc0 = n0; k0 = kt * 64; dst = W2T;
  }
  const int tid = threadIdx.x;
  {
    int r = tid >> 2, cs = (tid & 3) * 16;  // src row k0+r, 16 cols
    const float4* sp = (const float4*)(src + (size_t)(k0 + r) * Ns + nsrc0 + cs);
    unsigned short* tp = &tile[r * 72 + cs];
#pragma unroll
    for (int i = 0; i < 4; ++i) {
      float4 v = sp[i];
      tp[i * 4 + 0] = f2bf(v.x); tp[i * 4 + 1] = f2bf(v.y);
      tp[i * 4 + 2] = f2bf(v.z); tp[i * 4 + 3] = f2bf(v.w);
    }
  }
  __syncthreads();
  {
    int n = tid >> 2, ks = (tid & 3) * 16;  // dst row n0+n, 16 k's
    unsigned short buf[16];
#pragma unroll
    for (int e = 0; e < 16; ++e) buf[e] = tile[(ks + e) * 72 + n];
    unsigned short* dp = dst + (size_t)(n0 + n) * Kd + k0 + ks;
    *(short8*)dp = *(const short8*)&buf[0];
    *(short8*)(dp + 8) = *(const short8*)&buf[8];
  }
}

// ---------------- V transpose: QKVb V-cols -> Vg[b][h][d][key] ----------------
__global__ __launch_bounds__(256)
void k_vt(const unsigned short* __restrict__ QKV, unsigned short* __restrict__ Vg) {
  __shared__ unsigned short tile[64 * 72];
  const int t = blockIdx.x;
  const int kt = t & 63, h = (t >> 6) & 7, b = t >> 9;
  const int tid = threadIdx.x;
  {
    int r = tid >> 2, cs = (tid & 3) * 16;
    const unsigned short* sp = QKV + (size_t)(b * L + kt * 64 + r) * 1536 + 1024 + h * 64 + cs;
    unsigned short* tp = &tile[r * 72 + cs];
    *(short8*)tp = *(const short8*)sp;
    *(short8*)(tp + 8) = *(const short8*)(sp + 8);
  }
  __syncthreads();
  {
    int d = tid >> 2, ks = (tid & 3) * 16;
    unsigned short buf[16];
#pragma unroll
    for (int e = 0; e < 16; ++e) buf[e] = tile[(ks + e) * 72 + d];
    unsigned short* dp = Vg + ((size_t)(b * 8 + h) * 64 + d) * L + kt * 64 + ks;
    *(short8*)dp = *(const short8*)&buf[0];
    *(short8*)(dp + 8) = *(const short8*)&buf[8];
  }
}

// ---------------- bf16 MFMA GEMM (v2: double-buffered DMA staging) -----------
// Old schedule exposed full DMA latency every iter (sync; DMA; sync-drain).
// Now: tile k+1's DMA issues at the top of iter k and lands during the MFMA
// phase; ONE barrier per iter drains it + guards buffer reuse (same structure
// that took k_attn 45 -> ~27 us in round 9).
template <int EPI>
__global__ __launch_bounds__(256, 3)
void k_gemm(const unsigned short* __restrict__ A, const unsigned short* __restrict__ BT,
            const float* __restrict__ bias, void* __restrict__ Cout,
            const int klen, const int N) {
  __shared__ unsigned short lA[2][128 * 32];
  __shared__ unsigned short lB[2][128 * 32];
  const int tid = threadIdx.x;
  const int wave = tid >> 6, lane = tid & 63;
  const int quad = lane >> 4, l16 = lane & 15;
  const int m0 = blockIdx.y * 128, n0 = blockIdx.x * 128;
  const int wm = (wave >> 1) * 64, wn = (wave & 1) * 64;
  const int kbeg = blockIdx.z * klen;
  const size_t Kdim = (size_t)klen * gridDim.z;

  const floatx4 fzero = {0.f, 0.f, 0.f, 0.f};
  floatx4 acc[4][4];
#pragma unroll
  for (int i = 0; i < 4; ++i)
#pragma unroll
    for (int j = 0; j < 4; ++j) acc[i][j] = fzero;

  const int r0 = tid >> 2, o0 = (tid & 3) * 8;
  const int r1 = (256 + tid) >> 2, o1 = (tid & 3) * 8;
  const unsigned short* Ag0 = A + (size_t)(m0 + r0) * Kdim + kbeg + o0;
  const unsigned short* Ag1 = A + (size_t)(m0 + r1) * Kdim + kbeg + o1;
  const unsigned short* Bg0 = BT + (size_t)(n0 + r0) * Kdim + kbeg + o0;
  const unsigned short* Bg1 = BT + (size_t)(n0 + r1) * Kdim + kbeg + o1;

  auto stage = [&](int buf, int kt) {
    gl_lds16(Ag0 + kt, &lA[buf][wave * 512]);
    gl_lds16(Ag1 + kt, &lA[buf][(4 + wave) * 512]);
    gl_lds16(Bg0 + kt, &lB[buf][wave * 512]);
    gl_lds16(Bg1 + kt, &lB[buf][(4 + wave) * 512]);
  };

  stage(0, 0);
  __syncthreads();  // drain first tile's DMA

  int buf = 0;
  for (int kt = 0; kt < klen; kt += 32, buf ^= 1) {
    if (kt + 32 < klen) stage(buf ^ 1, kt + 32);  // async prefetch of next tile
    short8 af[4], bf[4];
#pragma unroll
    for (int i = 0; i < 4; ++i)
      af[i] = *(const short8*)&lA[buf][(wm + i * 16 + l16) * 32 + quad * 8];
#pragma unroll
    for (int j = 0; j < 4; ++j)
      bf[j] = *(const short8*)&lB[buf][(wn + j * 16 + l16) * 32 + quad * 8];
#pragma unroll
    for (int i = 0; i < 4; ++i)
#pragma unroll
      for (int j = 0; j < 4; ++j)
        acc[i][j] = __builtin_amdgcn_mfma_f32_16x16x32_bf16(af[i], bf[j], acc[i][j], 0, 0, 0);
    __syncthreads();  // drains prefetch DMA + guards buffer reuse (1 barrier/iter)
  }

  float* outf = (float*)Cout + (size_t)blockIdx.z * M * N;
#pragma unroll
  for (int j = 0; j < 4; ++j) {
    const int col = n0 + wn + j * 16 + l16;
    const float bv = (blockIdx.z == 0) ? bias[col] : 0.f;
#pragma unroll
    for (int i = 0; i < 4; ++i) {
      const int row = m0 + wm + i * 16 + quad * 4;
#pragma unroll
      for (int r = 0; r < 4; ++r) {
        float v = acc[i][j][r] + bv;
        if (EPI == 1) v = fmaxf(v, 0.f);
        if (EPI == 2)
          outf[(size_t)(row + r) * N + col] = v;
        else
          ((unsigned short*)Cout)[(size_t)(row + r) * N + col] = f2bf(v);
      }
    }
  }
}

// ---------------- banded flash attention (v7, unchanged from round 9) ---------
__global__ __launch_bounds__(256, 3)
void k_attn(const unsigned short* __restrict__ QKV, const unsigned short* __restrict__ Vg,
            unsigned short* __restrict__ attnb, const int* __restrict__ wptr) {
  const int W = wptr[0];  // 128
  __shared__ unsigned short Kt[2][4096];     // 64key x 64d tiles, swizzled (8 KB ea)
  __shared__ unsigned short Vt[2][4096];     // 64d x 64key tiles, swizzled
  __shared__ unsigned short Pb[4][16 * 72];  // 9216 B
  const int tid = threadIdx.x;
  const int wave = tid >> 6, lane = tid & 63;
  const int quad = lane >> 4, l16 = lane & 15;
  const int blk = blockIdx.x;
  const int qt = blk & 63, h = (blk >> 6) & 7, b = blk >> 9;  // qt fastest
  const int q0blk = qt * 64;
  const int q0 = q0blk + wave * 16;
  const float scale = 0.125f;  // 1/sqrt(64)

  const unsigned short* Kbase = QKV + (size_t)(b * L) * 1536 + 512 + h * 64;
  const unsigned short* Vh = Vg + (size_t)(b * 8 + h) * 64 * L;  // [d][key]

  auto stage = [&](int buf, int jbg) {
#pragma unroll
    for (int i = 0; i < 2; ++i) {
      int c = i * 256 + tid;
      int key = jbg + (c >> 3);
      int keyc = key < 0 ? 0 : (key > L - 1 ? L - 1 : key);  // P=0 there
      int dpart = (c & 7) ^ ((c >> 3) & 7);  // XOR swizzle
      gl_lds16(Kbase + (size_t)keyc * 1536 + dpart * 8,
               &Kt[buf][(i * 256 + wave * 64) * 8]);
    }
#pragma unroll
    for (int i = 0; i < 2; ++i) {
      int c = i * 256 + tid;
      int d = c >> 3;
      int kpart = (c & 7) ^ (d & 7);
      int kb = jbg + kpart * 8;
      kb = kb < 0 ? 0 : (kb > L - 8 ? L - 8 : kb);  // 8-aligned, P=0 where invalid
      gl_lds16(Vh + (size_t)d * L + kb,
               &Vt[buf][(i * 256 + wave * 64) * 8]);
    }
  };

  const unsigned short* Qp = QKV + (size_t)(b * L + q0 + l16) * 1536 + h * 64;
  short8 qf0 = *(const short8*)(Qp + quad * 8);
  short8 qf1 = *(const short8*)(Qp + 32 + quad * 8);

  const floatx4 fzero = {0.f, 0.f, 0.f, 0.f};
  floatx4 o[4];
#pragma unroll
  for (int i = 0; i < 4; ++i) o[i] = fzero;
  float lsum[4] = {0.f, 0.f, 0.f, 0.f};
  unsigned short* lp = Pb[wave];
  const int sw = l16 & 7;  // swizzle term for fragment reads

  stage(0, q0blk - 128);
  __syncthreads();

  for (int it = 0; it < 5; ++it) {  // 5 x 64-key tiles cover the 320-key band
    const int jbg = q0blk - 128 + it * 64;
    if (it < 4) stage((it + 1) & 1, jbg + 64);  // prefetch next tile (async DMA)
    const unsigned short* lk = Kt[it & 1];
    const unsigned short* lv = Vt[it & 1];
    floatx4 s[4];
#pragma unroll
    for (int ct = 0; ct < 4; ++ct) {
      int key = ct * 16 + l16;
      const short8 kf0 = *(const short8*)&lk[(key * 8 + (quad ^ sw)) * 8];
      const short8 kf1 = *(const short8*)&lk[(key * 8 + ((quad + 4) ^ sw)) * 8];
      floatx4 z = fzero;
      z = __builtin_amdgcn_mfma_f32_16x16x32_bf16(qf0, kf0, z, 0, 0, 0);
      z = __builtin_amdgcn_mfma_f32_16x16x32_bf16(qf1, kf1, z, 0, 0, 0);
      s[ct] = z;
    }
#pragma unroll
    for (int r = 0; r < 4; ++r) {
      int q = q0 + quad * 4 + r;
#pragma unroll
      for (int ct = 0; ct < 4; ++ct) {
        int key = jbg + ct * 16 + l16;
        int d = q - key; d = d < 0 ? -d : d;
        bool ok = (key >= 0) && (key < L) && (d <= W);
        float p = ok ? __expf(s[ct][r] * scale) : 0.f;  // fixed m=0, masked to 0
        lsum[r] += p;
        lp[(quad * 4 + r) * 72 + ct * 16 + l16] = f2bf(p);
      }
    }
    short8 pf0 = *(const short8*)&lp[l16 * 72 + quad * 8];
    short8 pf1 = *(const short8*)&lp[l16 * 72 + 32 + quad * 8];
#pragma unroll
    for (int nt = 0; nt < 4; ++nt) {
      int d = nt * 16 + l16;
      const short8 vf0 = *(const short8*)&lv[(d * 8 + (quad ^ sw)) * 8];
      const short8 vf1 = *(const short8*)&lv[(d * 8 + ((quad + 4) ^ sw)) * 8];
      o[nt] = __builtin_amdgcn_mfma_f32_16x16x32_bf16(pf0, vf0, o[nt], 0, 0, 0);
      o[nt] = __builtin_amdgcn_mfma_f32_16x16x32_bf16(pf1, vf1, o[nt], 0, 0, 0);
    }
    __syncthreads();  // drains next-tile DMA + guards buffer reuse
  }
#pragma unroll
  for (int r = 0; r < 4; ++r) {
#pragma unroll
    for (int dd = 1; dd < 16; dd <<= 1) lsum[r] += __shfl_xor(lsum[r], dd, 64);
  }
#pragma unroll
  for (int r = 0; r < 4; ++r) {
    float inv = 1.f / lsum[r];
    size_t base = (size_t)(b * L + q0 + quad * 4 + r) * 512 + h * 64;
#pragma unroll
    for (int nt = 0; nt < 4; ++nt)
      attnb[base + nt * 16 + l16] = f2bf(o[nt][r] * inv);
  }
}

// ---------------- fused residual + LayerNorm ----------------------------------
template <int NP>
__global__ __launch_bounds__(256, 2)
void k_res_ln(const float* __restrict__ t0, const float* __restrict__ t1,
              const float* __restrict__ res,
              const float* __restrict__ gamma, const float* __restrict__ beta,
              float* __restrict__ outf, unsigned short* __restrict__ outb) {
  const int wave = threadIdx.x >> 6, lane = threadIdx.x & 63;
  const int row = blockIdx.x * 4 + wave;
  const float4* tv = (const float4*)(t0 + (size_t)row * D);
  const float4* rv = (const float4*)(res + (size_t)row * D);
  float4 a0 = tv[lane], a1 = tv[lane + 64];
  float4 b0 = rv[lane], b1 = rv[lane + 64];
  float4 y0 = make_float4(a0.x + b0.x, a0.y + b0.y, a0.z + b0.z, a0.w + b0.w);
  float4 y1 = make_float4(a1.x + b1.x, a1.y + b1.y, a1.z + b1.z, a1.w + b1.w);
  if (NP == 2) {
    const float4* uv = (const float4*)(t1 + (size_t)row * D);
    float4 c0 = uv[lane], c1 = uv[lane + 64];
    y0.x += c0.x; y0.y += c0.y; y0.z += c0.z; y0.w += c0.w;
    y1.x += c1.x; y1.y += c1.y; y1.z += c1.z; y1.w += c1.w;
  }
  float s = y0.x + y0.y + y0.z + y0.w + y1.x + y1.y + y1.z + y1.w;
  float q = y0.x * y0.x + y0.y * y0.y + y0.z * y0.z + y0.w * y0.w +
            y1.x * y1.x + y1.y * y1.y + y1.z * y1.z + y1.w * y1.w;
#pragma unroll
  for (int d = 1; d < 64; d <<= 1) {
    s += __shfl_xor(s, d, 64);
    q += __shfl_xor(q, d, 64);
  }
  const float mean = s * (1.f / D);
  const float var = q * (1.f / D) - mean * mean;
  const float rstd = rsqrtf(var + LN_EPS);
  float4 g0 = ((const float4*)gamma)[lane], g1 = ((const float4*)gamma)[lane + 64];
  float4 e0 = ((const float4*)beta)[lane], e1 = ((const float4*)beta)[lane + 64];
  float4 o0 = make_float4((y0.x - mean) * rstd * g0.x + e0.x, (y0.y - mean) * rstd * g0.y + e0.y,
                          (y0.z - mean) * rstd * g0.z + e0.z, (y0.w - mean) * rstd * g0.w + e0.w);
  float4 o1 = make_float4((y1.x - mean) * rstd * g1.x + e1.x, (y1.y - mean) * rstd * g1.y + e1.y,
                          (y1.z - mean) * rstd * g1.z + e1.z, (y1.w - mean) * rstd * g1.w + e1.w);
  ((float4*)(outf + (size_t)row * D))[lane] = o0;
  ((float4*)(outf + (size_t)row * D))[lane + 64] = o1;
  if (outb) {
    ((ushort4*)(outb + (size_t)row * D))[lane] =
        make_ushort4(f2bf(o0.x), f2bf(o0.y), f2bf(o0.z), f2bf(o0.w));
    ((ushort4*)(outb + (size_t)row * D))[lane + 64] =
        make_ushort4(f2bf(o1.x), f2bf(o1.y), f2bf(o1.z), f2bf(o1.w));
  }
}

}  // namespace

extern "C" void kernel_launch(void* const* d_in, const int* in_sizes, int n_in,
                              void* d_out, int out_size, void* d_ws, size_t ws_size,
                              hipStream_t stream) {
  const float* x   = (const float*)d_in[0];
  const float* Wq  = (const float*)d_in[1];
  const float* bq  = (const float*)d_in[2];
  const float* Wk  = (const float*)d_in[3];
  const float* bk  = (const float*)d_in[4];
  const float* Wv  = (const float*)d_in[5];
  const float* bv  = (const float*)d_in[6];
  const float* Wo  = (const float*)d_in[7];
  const float* bo  = (const float*)d_in[8];
  const float* g1  = (const float*)d_in[9];
  const float* be1 = (const float*)d_in[10];
  const float* W1  = (const float*)d_in[11];
  const float* b1  = (const float*)d_in[12];
  const float* W2  = (const float*)d_in[13];
  const float* b2  = (const float*)d_in[14];
  const float* g2  = (const float*)d_in[15];
  const float* be2 = (const float*)d_in[16];
  const int* wptr  = (const int*)d_in[17];
  float* out = (float*)d_out;

  char* w = (char*)d_ws;
  size_t off = 0;
  auto take = [&](size_t bytes) -> void* {
    void* p = w + off;
    off += (bytes + 255) & ~(size_t)255;
    return p;
  };
  unsigned short* Xb    = (unsigned short*)take((size_t)M * D * 2);      // 8 MiB
  unsigned short* QKVb  = (unsigned short*)take((size_t)M * 1536 * 2);   // 24 MiB
  unsigned short* attnb = (unsigned short*)take((size_t)M * D * 2);      // 8 MiB
  unsigned short* Vg    = (unsigned short*)take((size_t)M * D * 2);      // 8 MiB (V^T per head)
  unsigned short* WqkvT = (unsigned short*)take((size_t)1536 * 512 * 2); // 1.5 MiB
  unsigned short* WoT   = (unsigned short*)take((size_t)512 * 512 * 2);  // 0.5 MiB
  unsigned short* W1T   = (unsigned short*)take((size_t)2048 * 512 * 2); // 2 MiB
  unsigned short* W2T   = (unsigned short*)take((size_t)512 * 2048 * 2); // 2 MiB
  float* bqkv           = (float*)take(1536 * 4);
  float* tbuf           = (float*)take((size_t)2 * M * D * 4);           // 32 MiB (2 split-K partials)
  float* hbuf           = (float*)take((size_t)M * D * 4);               // 16 MiB
  unsigned short* hb    = (unsigned short*)take((size_t)M * D * 2);      // 8 MiB
  unsigned short* ffb   = (unsigned short*)take((size_t)M * FF * 2);     // 32 MiB

  k_prep<<<4870, 256, 0, stream>>>(x, Wq, Wk, Wv, Wo, W1, W2, bq, bk, bv,
                                   Xb, WqkvT, WoT, W1T, W2T, bqkv);
  k_gemm<0><<<dim3(12, 64, 1), 256, 0, stream>>>(Xb, WqkvT, bqkv, QKVb, 512, 1536);
  k_vt<<<1024, 256, 0, stream>>>(QKVb, Vg);
  k_attn<<<B * H * (L / 64), 256, 0, stream>>>(QKVb, Vg, attnb, wptr);
  k_gemm<2><<<dim3(4, 64, 2), 256, 0, stream>>>(attnb, WoT, bo, tbuf, 256, 512);
  k_res_ln<2><<<M / 4, 256, 0, stream>>>(tbuf, tbuf + (size_t)M * D, x, g1, be1, hbuf, hb);
  k_gemm<1><<<dim3(16, 64, 1), 256, 0, stream>>>(hb, W1T, b1, ffb, 512, 2048);
  k_gemm<2><<<dim3(4, 64, 2), 256, 0, stream>>>(ffb, W2T, b2, tbuf, 1024, 512);
  k_res_ln<2><<<M / 4, 256, 0, stream>>>(tbuf, tbuf + (size_t)M * D, hbuf, g2, be2, out, nullptr);
}

// Round 11
// 250.078 us; speedup vs baseline: 1.0977x; 1.0229x over previous
//
#include <hip/hip_runtime.h>

namespace {

constexpr int B = 2, L = 4096, D = 512, H = 8, FF = 2048;
constexpr int M = B * L; // 8192
constexpr float LN_EPS = 1e-5f;

typedef __attribute__((ext_vector_type(8))) short short8;
typedef __attribute__((ext_vector_type(4))) float floatx4;

typedef __attribute__((address_space(3))) unsigned int lds_uint;
typedef const __attribute__((address_space(1))) unsigned int glob_uint;

__device__ __forceinline__ void gl_lds16(const unsigned short* g, unsigned short* l) {
  // async global->LDS, 16B/lane; LDS dest = wave-uniform base + lane*16 (m104)
  __builtin_amdgcn_global_load_lds((glob_uint*)g, (lds_uint*)l, 16, 0, 0);
}

__device__ __forceinline__ unsigned short f2bf(float f) {
  union { float f; unsigned u; } v; v.f = f;
  unsigned r = v.u + 0x7FFFu + ((v.u >> 16) & 1u);
  return (unsigned short)(r >> 16);
}

__device__ __forceinline__ float bf2f(unsigned short b) {
  union { unsigned u; float f; } v; v.u = ((unsigned)b) << 16;
  return v.f;
}

// ---------------- fused prep: x->bf16 + bias concat + weight transposes ------
__global__ __launch_bounds__(256)
void k_prep(const float* __restrict__ x,
            const float* __restrict__ Wq, const float* __restrict__ Wk,
            const float* __restrict__ Wv, const float* __restrict__ Wo,
            const float* __restrict__ W1, const float* __restrict__ W2,
            const float* __restrict__ bq, const float* __restrict__ bk,
            const float* __restrict__ bv,
            unsigned short* __restrict__ Xb,
            unsigned short* __restrict__ WqkvT, unsigned short* __restrict__ WoT,
            unsigned short* __restrict__ W1T, unsigned short* __restrict__ W2T,
            float* __restrict__ bqkv) {
  __shared__ unsigned short tile[64 * 72];
  if (blockIdx.x < 4102) {
    int tid = blockIdx.x * blockDim.x + threadIdx.x;
    if (tid < 1048576) {  // x: 4 elems per thread (M*D = 4194304)
      float4 v = ((const float4*)x)[tid];
      ((ushort4*)Xb)[tid] = make_ushort4(f2bf(v.x), f2bf(v.y), f2bf(v.z), f2bf(v.w));
      return;
    }
    int u = tid - 1048576;
    if (u < 1536) bqkv[u] = (u < 512) ? bq[u] : (u < 1024 ? bk[u - 512] : bv[u - 1024]);
    return;
  }
  const int t = blockIdx.x - 4102;
  const float* src; unsigned short* dst; int Ns, Kd, n0, k0, nsrc0;
  if (t < 192) {        // WqkvT [1536][512] from Wq/Wk/Wv [512][512]
    int nt = t % 24, kt = t / 24; int ng = nt * 64;
    src = ng < 512 ? Wq : (ng < 1024 ? Wk : Wv);
    Ns = 512; Kd = 512; n0 = ng; nsrc0 = ng & 511; k0 = kt * 64; dst = WqkvT;
  } else if (t < 256) { // WoT [512][512] from Wo [512][512]
    int u = t - 192; int nt = u % 8, kt = u / 8;
    src = Wo; Ns = 512; Kd = 512; n0 = nt * 64; nsrc0 = n0; k0 = kt * 64; dst = WoT;
  } else if (t < 512) { // W1T [2048][512] from W1 [512][2048]
    int u = t - 256; int nt = u % 32, kt = u / 32;
    src = W1; Ns = 2048; Kd = 512; n0 = nt * 64; nsrc0 = n0; k0 = kt * 64; dst = W1T;
  } else {              // W2T [512][2048] from W2 [2048][512]
    int u = t - 512; int nt = u % 8, kt = u / 8;
    src = W2; Ns = 512; Kd = 2048; n0 = nt * 64; nsrc0 = n0; k0 = kt * 64; dst = W2T;
  }
  const int tid = threadIdx.x;
  {
    int r = tid >> 2, cs = (tid & 3) * 16;  // src row k0+r, 16 cols
    const float4* sp = (const float4*)(src + (size_t)(k0 + r) * Ns + nsrc0 + cs);
    unsigned short* tp = &tile[r * 72 + cs];
#pragma unroll
    for (int i = 0; i < 4; ++i) {
      float4 v = sp[i];
      tp[i * 4 + 0] = f2bf(v.x); tp[i * 4 + 1] = f2bf(v.y);
      tp[i * 4 + 2] = f2bf(v.z); tp[i * 4 + 3] = f2bf(v.w);
    }
  }
  __syncthreads();
  {
    int n = tid >> 2, ks = (tid & 3) * 16;  // dst row n0+n, 16 k's
    unsigned short buf[16];
#pragma unroll
    for (int e = 0; e < 16; ++e) buf[e] = tile[(ks + e) * 72 + n];
    unsigned short* dp = dst + (size_t)(n0 + n) * Kd + k0 + ks;
    *(short8*)dp = *(const short8*)&buf[0];
    *(short8*)(dp + 8) = *(const short8*)&buf[8];
  }
}

// ---------------- bf16 MFMA GEMM (double-buffered DMA staging) ---------------
// EPI: 0 = bf16 out, 1 = bf16 out + ReLU, 2 = f32 out (split-K partials),
//      3 = QKV fused: Q/K cols -> Cout (bf16), V cols -> Vout TRANSPOSED
//          ([b][h][d][key]; each lane's 4 acc rows = 4 consecutive keys at
//          fixed d -> one 8B store; branch is block-uniform on n0).
template <int EPI>
__global__ __launch_bounds__(256, 3)
void k_gemm(const unsigned short* __restrict__ A, const unsigned short* __restrict__ BT,
            const float* __restrict__ bias, void* __restrict__ Cout,
            unsigned short* __restrict__ Vout,
            const int klen, const int N) {
  __shared__ unsigned short lA[2][128 * 32];
  __shared__ unsigned short lB[2][128 * 32];
  const int tid = threadIdx.x;
  const int wave = tid >> 6, lane = tid & 63;
  const int quad = lane >> 4, l16 = lane & 15;
  const int m0 = blockIdx.y * 128, n0 = blockIdx.x * 128;
  const int wm = (wave >> 1) * 64, wn = (wave & 1) * 64;
  const int kbeg = blockIdx.z * klen;
  const size_t Kdim = (size_t)klen * gridDim.z;

  const floatx4 fzero = {0.f, 0.f, 0.f, 0.f};
  floatx4 acc[4][4];
#pragma unroll
  for (int i = 0; i < 4; ++i)
#pragma unroll
    for (int j = 0; j < 4; ++j) acc[i][j] = fzero;

  const int r0 = tid >> 2, o0 = (tid & 3) * 8;
  const int r1 = (256 + tid) >> 2, o1 = (tid & 3) * 8;
  const unsigned short* Ag0 = A + (size_t)(m0 + r0) * Kdim + kbeg + o0;
  const unsigned short* Ag1 = A + (size_t)(m0 + r1) * Kdim + kbeg + o1;
  const unsigned short* Bg0 = BT + (size_t)(n0 + r0) * Kdim + kbeg + o0;
  const unsigned short* Bg1 = BT + (size_t)(n0 + r1) * Kdim + kbeg + o1;

  auto stage = [&](int buf, int kt) {
    gl_lds16(Ag0 + kt, &lA[buf][wave * 512]);
    gl_lds16(Ag1 + kt, &lA[buf][(4 + wave) * 512]);
    gl_lds16(Bg0 + kt, &lB[buf][wave * 512]);
    gl_lds16(Bg1 + kt, &lB[buf][(4 + wave) * 512]);
  };

  stage(0, 0);
  __syncthreads();  // drain first tile's DMA

  int buf = 0;
  for (int kt = 0; kt < klen; kt += 32, buf ^= 1) {
    if (kt + 32 < klen) stage(buf ^ 1, kt + 32);  // async prefetch of next tile
    short8 af[4], bf[4];
#pragma unroll
    for (int i = 0; i < 4; ++i)
      af[i] = *(const short8*)&lA[buf][(wm + i * 16 + l16) * 32 + quad * 8];
#pragma unroll
    for (int j = 0; j < 4; ++j)
      bf[j] = *(const short8*)&lB[buf][(wn + j * 16 + l16) * 32 + quad * 8];
#pragma unroll
    for (int i = 0; i < 4; ++i)
#pragma unroll
      for (int j = 0; j < 4; ++j)
        acc[i][j] = __builtin_amdgcn_mfma_f32_16x16x32_bf16(af[i], bf[j], acc[i][j], 0, 0, 0);
    __syncthreads();  // drains prefetch DMA + guards buffer reuse
  }

  float* outf = (float*)Cout + (size_t)blockIdx.z * M * N;
  const bool vblock = (EPI == 3) && (n0 >= 1024);  // block-uniform
#pragma unroll
  for (int j = 0; j < 4; ++j) {
    const int col = n0 + wn + j * 16 + l16;
    const float bv = (blockIdx.z == 0) ? bias[col] : 0.f;
#pragma unroll
    for (int i = 0; i < 4; ++i) {
      const int row = m0 + wm + i * 16 + quad * 4;
      if (EPI == 3 && vblock) {
        const int hh = (col - 1024) >> 6, dd = (col - 1024) & 63;
        const int bb = row >> 12, keyl = row & 4095;  // 128-tiles never cross b
        ushort4 pk = make_ushort4(f2bf(acc[i][j][0] + bv), f2bf(acc[i][j][1] + bv),
                                  f2bf(acc[i][j][2] + bv), f2bf(acc[i][j][3] + bv));
        *(ushort4*)(Vout + ((size_t)(bb * 8 + hh) * 64 + dd) * L + keyl) = pk;
      } else {
#pragma unroll
        for (int r = 0; r < 4; ++r) {
          float v = acc[i][j][r] + bv;
          if (EPI == 1) v = fmaxf(v, 0.f);
          if (EPI == 2)
            outf[(size_t)(row + r) * N + col] = v;
          else
            ((unsigned short*)Cout)[(size_t)(row + r) * N + col] = f2bf(v);
        }
      }
    }
  }
}

// ---------------- banded flash attention (v7, round-9 structure) --------------
__global__ __launch_bounds__(256, 3)
void k_attn(const unsigned short* __restrict__ QKV, const unsigned short* __restrict__ Vg,
            unsigned short* __restrict__ attnb, const int* __restrict__ wptr) {
  const int W = wptr[0];  // 128
  __shared__ unsigned short Kt[2][4096];     // 64key x 64d tiles, swizzled (8 KB ea)
  __shared__ unsigned short Vt[2][4096];     // 64d x 64key tiles, swizzled
  __shared__ unsigned short Pb[4][16 * 72];  // 9216 B
  const int tid = threadIdx.x;
  const int wave = tid >> 6, lane = tid & 63;
  const int quad = lane >> 4, l16 = lane & 15;
  const int blk = blockIdx.x;
  const int qt = blk & 63, h = (blk >> 6) & 7, b = blk >> 9;  // qt fastest
  const int q0blk = qt * 64;
  const int q0 = q0blk + wave * 16;
  const float scale = 0.125f;  // 1/sqrt(64)

  const unsigned short* Kbase = QKV + (size_t)(b * L) * 1536 + 512 + h * 64;
  const unsigned short* Vh = Vg + (size_t)(b * 8 + h) * 64 * L;  // [d][key]

  auto stage = [&](int buf, int jbg) {
#pragma unroll
    for (int i = 0; i < 2; ++i) {
      int c = i * 256 + tid;
      int key = jbg + (c >> 3);
      int keyc = key < 0 ? 0 : (key > L - 1 ? L - 1 : key);  // P=0 there
      int dpart = (c & 7) ^ ((c >> 3) & 7);  // XOR swizzle
      gl_lds16(Kbase + (size_t)keyc * 1536 + dpart * 8,
               &Kt[buf][(i * 256 + wave * 64) * 8]);
    }
#pragma unroll
    for (int i = 0; i < 2; ++i) {
      int c = i * 256 + tid;
      int d = c >> 3;
      int kpart = (c & 7) ^ (d & 7);
      int kb = jbg + kpart * 8;
      kb = kb < 0 ? 0 : (kb > L - 8 ? L - 8 : kb);  // 8-aligned, P=0 where invalid
      gl_lds16(Vh + (size_t)d * L + kb,
               &Vt[buf][(i * 256 + wave * 64) * 8]);
    }
  };

  const unsigned short* Qp = QKV + (size_t)(b * L + q0 + l16) * 1536 + h * 64;
  short8 qf0 = *(const short8*)(Qp + quad * 8);
  short8 qf1 = *(const short8*)(Qp + 32 + quad * 8);

  const floatx4 fzero = {0.f, 0.f, 0.f, 0.f};
  floatx4 o[4];
#pragma unroll
  for (int i = 0; i < 4; ++i) o[i] = fzero;
  float lsum[4] = {0.f, 0.f, 0.f, 0.f};
  unsigned short* lp = Pb[wave];
  const int sw = l16 & 7;  // swizzle term for fragment reads

  stage(0, q0blk - 128);
  __syncthreads();

  for (int it = 0; it < 5; ++it) {  // 5 x 64-key tiles cover the 320-key band
    const int jbg = q0blk - 128 + it * 64;
    if (it < 4) stage((it + 1) & 1, jbg + 64);  // prefetch next tile (async DMA)
    const unsigned short* lk = Kt[it & 1];
    const unsigned short* lv = Vt[it & 1];
    floatx4 s[4];
#pragma unroll
    for (int ct = 0; ct < 4; ++ct) {
      int key = ct * 16 + l16;
      const short8 kf0 = *(const short8*)&lk[(key * 8 + (quad ^ sw)) * 8];
      const short8 kf1 = *(const short8*)&lk[(key * 8 + ((quad + 4) ^ sw)) * 8];
      floatx4 z = fzero;
      z = __builtin_amdgcn_mfma_f32_16x16x32_bf16(qf0, kf0, z, 0, 0, 0);
      z = __builtin_amdgcn_mfma_f32_16x16x32_bf16(qf1, kf1, z, 0, 0, 0);
      s[ct] = z;
    }
#pragma unroll
    for (int r = 0; r < 4; ++r) {
      int q = q0 + quad * 4 + r;
#pragma unroll
      for (int ct = 0; ct < 4; ++ct) {
        int key = jbg + ct * 16 + l16;
        int d = q - key; d = d < 0 ? -d : d;
        bool ok = (key >= 0) && (key < L) && (d <= W);
        float p = ok ? __expf(s[ct][r] * scale) : 0.f;  // fixed m=0, masked to 0
        lsum[r] += p;
        lp[(quad * 4 + r) * 72 + ct * 16 + l16] = f2bf(p);
      }
    }
    short8 pf0 = *(const short8*)&lp[l16 * 72 + quad * 8];
    short8 pf1 = *(const short8*)&lp[l16 * 72 + 32 + quad * 8];
#pragma unroll
    for (int nt = 0; nt < 4; ++nt) {
      int d = nt * 16 + l16;
      const short8 vf0 = *(const short8*)&lv[(d * 8 + (quad ^ sw)) * 8];
      const short8 vf1 = *(const short8*)&lv[(d * 8 + ((quad + 4) ^ sw)) * 8];
      o[nt] = __builtin_amdgcn_mfma_f32_16x16x32_bf16(pf0, vf0, o[nt], 0, 0, 0);
      o[nt] = __builtin_amdgcn_mfma_f32_16x16x32_bf16(pf1, vf1, o[nt], 0, 0, 0);
    }
    __syncthreads();  // drains next-tile DMA + guards buffer reuse
  }
#pragma unroll
  for (int r = 0; r < 4; ++r) {
#pragma unroll
    for (int dd = 1; dd < 16; dd <<= 1) lsum[r] += __shfl_xor(lsum[r], dd, 64);
  }
#pragma unroll
  for (int r = 0; r < 4; ++r) {
    float inv = 1.f / lsum[r];
    size_t base = (size_t)(b * L + q0 + quad * 4 + r) * 512 + h * 64;
#pragma unroll
    for (int nt = 0; nt < 4; ++nt)
      attnb[base + nt * 16 + l16] = f2bf(o[nt][r] * inv);
  }
}

// ---------------- fused residual + LayerNorm ----------------------------------
// y = t0 + t1 + res; out = LN(y)*g+b. RESBF: res is bf16. outf/outb optional.
template <int RESBF>
__global__ __launch_bounds__(256, 2)
void k_res_ln(const float* __restrict__ t0, const float* __restrict__ t1,
              const void* __restrict__ res,
              const float* __restrict__ gamma, const float* __restrict__ beta,
              float* __restrict__ outf, unsigned short* __restrict__ outb) {
  const int wave = threadIdx.x >> 6, lane = threadIdx.x & 63;
  const int row = blockIdx.x * 4 + wave;
  const float4* tv = (const float4*)(t0 + (size_t)row * D);
  float4 a0 = tv[lane], a1 = tv[lane + 64];
  float4 b0, b1;
  if (RESBF) {
    const ushort4* rv = (const ushort4*)((const unsigned short*)res + (size_t)row * D);
    ushort4 u0 = rv[lane], u1 = rv[lane + 64];
    b0 = make_float4(bf2f(u0.x), bf2f(u0.y), bf2f(u0.z), bf2f(u0.w));
    b1 = make_float4(bf2f(u1.x), bf2f(u1.y), bf2f(u1.z), bf2f(u1.w));
  } else {
    const float4* rv = (const float4*)((const float*)res + (size_t)row * D);
    b0 = rv[lane]; b1 = rv[lane + 64];
  }
  float4 y0 = make_float4(a0.x + b0.x, a0.y + b0.y, a0.z + b0.z, a0.w + b0.w);
  float4 y1 = make_float4(a1.x + b1.x, a1.y + b1.y, a1.z + b1.z, a1.w + b1.w);
  {
    const float4* uv = (const float4*)(t1 + (size_t)row * D);
    float4 c0 = uv[lane], c1 = uv[lane + 64];
    y0.x += c0.x; y0.y += c0.y; y0.z += c0.z; y0.w += c0.w;
    y1.x += c1.x; y1.y += c1.y; y1.z += c1.z; y1.w += c1.w;
  }
  float s = y0.x + y0.y + y0.z + y0.w + y1.x + y1.y + y1.z + y1.w;
  float q = y0.x * y0.x + y0.y * y0.y + y0.z * y0.z + y0.w * y0.w +
            y1.x * y1.x + y1.y * y1.y + y1.z * y1.z + y1.w * y1.w;
#pragma unroll
  for (int d = 1; d < 64; d <<= 1) {
    s += __shfl_xor(s, d, 64);
    q += __shfl_xor(q, d, 64);
  }
  const float mean = s * (1.f / D);
  const float var = q * (1.f / D) - mean * mean;
  const float rstd = rsqrtf(var + LN_EPS);
  float4 g0 = ((const float4*)gamma)[lane], g1 = ((const float4*)gamma)[lane + 64];
  float4 e0 = ((const float4*)beta)[lane], e1 = ((const float4*)beta)[lane + 64];
  float4 o0 = make_float4((y0.x - mean) * rstd * g0.x + e0.x, (y0.y - mean) * rstd * g0.y + e0.y,
                          (y0.z - mean) * rstd * g0.z + e0.z, (y0.w - mean) * rstd * g0.w + e0.w);
  float4 o1 = make_float4((y1.x - mean) * rstd * g1.x + e1.x, (y1.y - mean) * rstd * g1.y + e1.y,
                          (y1.z - mean) * rstd * g1.z + e1.z, (y1.w - mean) * rstd * g1.w + e1.w);
  if (outf) {
    ((float4*)(outf + (size_t)row * D))[lane] = o0;
    ((float4*)(outf + (size_t)row * D))[lane + 64] = o1;
  }
  if (outb) {
    ((ushort4*)(outb + (size_t)row * D))[lane] =
        make_ushort4(f2bf(o0.x), f2bf(o0.y), f2bf(o0.z), f2bf(o0.w));
    ((ushort4*)(outb + (size_t)row * D))[lane + 64] =
        make_ushort4(f2bf(o1.x), f2bf(o1.y), f2bf(o1.z), f2bf(o1.w));
  }
}

}  // namespace

extern "C" void kernel_launch(void* const* d_in, const int* in_sizes, int n_in,
                              void* d_out, int out_size, void* d_ws, size_t ws_size,
                              hipStream_t stream) {
  const float* x   = (const float*)d_in[0];
  const float* Wq  = (const float*)d_in[1];
  const float* bq  = (const float*)d_in[2];
  const float* Wk  = (const float*)d_in[3];
  const float* bk  = (const float*)d_in[4];
  const float* Wv  = (const float*)d_in[5];
  const float* bv  = (const float*)d_in[6];
  const float* Wo  = (const float*)d_in[7];
  const float* bo  = (const float*)d_in[8];
  const float* g1  = (const float*)d_in[9];
  const float* be1 = (const float*)d_in[10];
  const float* W1  = (const float*)d_in[11];
  const float* b1  = (const float*)d_in[12];
  const float* W2  = (const float*)d_in[13];
  const float* b2  = (const float*)d_in[14];
  const float* g2  = (const float*)d_in[15];
  const float* be2 = (const float*)d_in[16];
  const int* wptr  = (const int*)d_in[17];
  float* out = (float*)d_out;

  char* w = (char*)d_ws;
  size_t off = 0;
  auto take = [&](size_t bytes) -> void* {
    void* p = w + off;
    off += (bytes + 255) & ~(size_t)255;
    return p;
  };
  unsigned short* Xb    = (unsigned short*)take((size_t)M * D * 2);      // 8 MiB
  unsigned short* QKVb  = (unsigned short*)take((size_t)M * 1536 * 2);   // 24 MiB
  unsigned short* attnb = (unsigned short*)take((size_t)M * D * 2);      // 8 MiB
  unsigned short* Vg    = (unsigned short*)take((size_t)M * D * 2);      // 8 MiB (V^T per head)
  unsigned short* WqkvT = (unsigned short*)take((size_t)1536 * 512 * 2); // 1.5 MiB
  unsigned short* WoT   = (unsigned short*)take((size_t)512 * 512 * 2);  // 0.5 MiB
  unsigned short* W1T   = (unsigned short*)take((size_t)2048 * 512 * 2); // 2 MiB
  unsigned short* W2T   = (unsigned short*)take((size_t)512 * 2048 * 2); // 2 MiB
  float* bqkv           = (float*)take(1536 * 4);
  float* tbuf           = (float*)take((size_t)2 * M * D * 4);           // 32 MiB (2 split-K partials)
  unsigned short* hb    = (unsigned short*)take((size_t)M * D * 2);      // 8 MiB
  unsigned short* ffb   = (unsigned short*)take((size_t)M * FF * 2);     // 32 MiB

  k_prep<<<4870, 256, 0, stream>>>(x, Wq, Wk, Wv, Wo, W1, W2, bq, bk, bv,
                                   Xb, WqkvT, WoT, W1T, W2T, bqkv);
  // QKV: Q/K -> QKVb, V -> Vg transposed (k_vt eliminated)
  k_gemm<3><<<dim3(12, 64, 1), 256, 0, stream>>>(Xb, WqkvT, bqkv, QKVb, Vg, 512, 1536);
  k_attn<<<B * H * (L / 64), 256, 0, stream>>>(QKVb, Vg, attnb, wptr);
  k_gemm<2><<<dim3(4, 64, 2), 256, 0, stream>>>(attnb, WoT, bo, tbuf, nullptr, 256, 512);
  // h = LN1(x + t0 + t1) -> hb (bf16 only; fp32 h dropped)
  k_res_ln<0><<<M / 4, 256, 0, stream>>>(tbuf, tbuf + (size_t)M * D, x, g1, be1, nullptr, hb);
  k_gemm<1><<<dim3(16, 64, 1), 256, 0, stream>>>(hb, W1T, b1, ffb, nullptr, 512, 2048);
  k_gemm<2><<<dim3(4, 64, 2), 256, 0, stream>>>(ffb, W2T, b2, tbuf, nullptr, 1024, 512);
  // out = LN2(hb + t0 + t1), residual from bf16 h
  k_res_ln<1><<<M / 4, 256, 0, stream>>>(tbuf, tbuf + (size_t)M * D, hb, g2, be2, out, nullptr);
}